// Round 1
// baseline (83.830 us; speedup 1.0000x reference)
//
#include <hip/hip_runtime.h>
#include <hip/hip_bf16.h>

// Problem constants
#define B_ROWS 65536
#define DIN    784
#define DHID   100
#define DOUT   10

// Padded GEMM1 geometry
#define KP     832          // K padded to 26*32
#define NP     112          // N padded to 7*16
#define KC     64           // K chunk per staging step
#define NCHUNK 13           // 832/64
#define TM     128          // rows per block

// LDS strides (in elements). 72 bf16 = 144 B = 16*9 -> b128 reads stay 16B aligned,
// bank pattern row*36 dwords -> 4*row mod 32 -> 2-way conflict max (free per m136).
#define SX     72
#define SW     72
#define SH     113          // f32 h stride: 113 mod 32 = 17 (odd) -> conflict-free column reads

typedef float  f32x4  __attribute__((ext_vector_type(4)));
typedef __bf16 bf16x8 __attribute__((ext_vector_type(8)));

__device__ inline unsigned short f2bf(float f) {
    unsigned int u = __builtin_bit_cast(unsigned int, f);
    u = (u + 0x7fffu + ((u >> 16) & 1u)) >> 16;   // RNE
    return (unsigned short)u;
}

// ---- prep: W1 [784][100] f32 -> W1T bf16 [112][832] (zero padded), freq_out = freq_in
__global__ void prep_kernel(const float* __restrict__ W1,
                            const float* __restrict__ freq_in,
                            unsigned short* __restrict__ w1t,
                            float* __restrict__ freq_out) {
    int idx = blockIdx.x * 256 + threadIdx.x;
    if (idx < NP * KP) {
        int row = idx / KP;   // output column (0..111)
        int k   = idx % KP;   // input k (0..831)
        float v = (row < DHID && k < DIN) ? W1[k * DHID + row] : 0.f;
        w1t[idx] = f2bf(v);
    }
    if (idx < DHID) freq_out[idx] = freq_in[idx];
}

union SmemU {
    struct { unsigned short x[TM * SX]; unsigned short w[NP * SW]; } s; // staging (34.5 KB)
    float h[TM * SH];                                                   // h tile (56.5 KB)
};

__global__ __launch_bounds__(256)
void fused_mlp_kernel(const float* __restrict__ x,
                      const unsigned short* __restrict__ w1t,
                      const float* __restrict__ b1,
                      const float* __restrict__ W2,
                      const float* __restrict__ b2,
                      float* __restrict__ outp,
                      float* __restrict__ freq_out) {
    __shared__ SmemU u;
    __shared__ float b1s[NP];
    __shared__ float w2s[DHID * DOUT];
    __shared__ float b2s[DOUT];

    const int tid  = threadIdx.x;
    const int lane = tid & 63;
    const int wave = tid >> 6;        // 0..3
    const int r16  = lane & 15;
    const int q    = lane >> 4;       // 0..3

    // constant staging (consumed only after several __syncthreads)
    for (int i = tid; i < NP; i += 256) b1s[i] = (i < DHID) ? b1[i] : 0.f;
    for (int i = tid; i < DHID * DOUT; i += 256) w2s[i] = W2[i];
    if (tid < DOUT) b2s[tid] = b2[tid];

    const float* xrow = x + (size_t)blockIdx.x * TM * DIN;

    f32x4 acc[2][7] = {};

    for (int c = 0; c < NCHUNK; ++c) {
        __syncthreads();   // previous compute done before overwriting staging
        // ---- stage x chunk: 128 rows x 64 f32 -> bf16 LDS
        #pragma unroll
        for (int i = 0; i < 8; ++i) {
            int idx = i * 256 + tid;            // 0..2047
            int row = idx >> 4;
            int kq  = idx & 15;
            int kcol = c * KC + kq * 4;
            float4 v = make_float4(0.f, 0.f, 0.f, 0.f);
            if (kcol < DIN) v = *(const float4*)(xrow + row * DIN + kcol);
            ushort4 w;
            w.x = f2bf(v.x); w.y = f2bf(v.y); w.z = f2bf(v.z); w.w = f2bf(v.w);
            *(ushort4*)&u.s.x[row * SX + kq * 4] = w;
        }
        // ---- stage W1T chunk: 112 rows x 64 bf16
        #pragma unroll
        for (int i = 0; i < 4; ++i) {
            int idx = i * 256 + tid;            // need < 896
            if (idx < 896) {
                int rowc = idx >> 3;            // 0..111
                int kq   = idx & 7;
                uint4 v = *(const uint4*)(w1t + rowc * KP + c * KC + kq * 8);
                *(uint4*)&u.s.w[rowc * SW + kq * 8] = v;
            }
        }
        __syncthreads();
        // ---- compute: 2 k-steps of 32
        #pragma unroll
        for (int ks = 0; ks < 2; ++ks) {
            const int koff = ks * 32 + q * 8;
            bf16x8 a[2], b[7];
            #pragma unroll
            for (int m = 0; m < 2; ++m)
                a[m] = *(const bf16x8*)&u.s.x[(wave * 32 + m * 16 + r16) * SX + koff];
            #pragma unroll
            for (int n = 0; n < 7; ++n)
                b[n] = *(const bf16x8*)&u.s.w[(n * 16 + r16) * SW + koff];
            #pragma unroll
            for (int m = 0; m < 2; ++m)
                #pragma unroll
                for (int n = 0; n < 7; ++n)
                    acc[m][n] = __builtin_amdgcn_mfma_f32_16x16x32_bf16(a[m], b[n], acc[m][n], 0, 0, 0);
        }
    }

    // ---- epilogue: bias + relu -> h tile in LDS (aliases staging)
    __syncthreads();
    #pragma unroll
    for (int m = 0; m < 2; ++m)
        #pragma unroll
        for (int n = 0; n < 7; ++n)
            #pragma unroll
            for (int i = 0; i < 4; ++i) {
                int row = wave * 32 + m * 16 + q * 4 + i;
                int col = n * 16 + r16;
                float v = acc[m][n][i] + b1s[col];
                u.h[row * SH + col] = v > 0.f ? v : 0.f;
            }
    __syncthreads();

    // ---- threads 0..127: GEMM2 + softmax; threads 128..227: freq count
    if (tid < TM) {
        const int r = tid;
        float lg[DOUT];
        #pragma unroll
        for (int k = 0; k < DOUT; ++k) lg[k] = b2s[k];
        for (int j = 0; j < DHID; ++j) {
            float hv = u.h[r * SH + j];
            #pragma unroll
            for (int k = 0; k < DOUT; ++k) lg[k] += hv * w2s[j * DOUT + k];
        }
        float mx = lg[0];
        #pragma unroll
        for (int k = 1; k < DOUT; ++k) mx = fmaxf(mx, lg[k]);
        float s = 0.f;
        #pragma unroll
        for (int k = 0; k < DOUT; ++k) { lg[k] = __expf(lg[k] - mx); s += lg[k]; }
        float inv = 1.f / s;
        float* o = outp + ((size_t)blockIdx.x * TM + r) * DOUT;
        #pragma unroll
        for (int k = 0; k < DOUT; ++k) o[k] = lg[k] * inv;
    } else if (tid < TM + DHID) {
        const int j = tid - TM;
        int rmax = (blockIdx.x == gridDim.x - 1) ? (TM - 1) : TM;  // skip global last row
        int cnt = 0;
        for (int r = 0; r < rmax; ++r) cnt += (u.h[r * SH + j] > 0.f) ? 1 : 0;
        atomicAdd(freq_out + j, (float)cnt);  // integer-valued -> exact & order independent
    }
}

extern "C" void kernel_launch(void* const* d_in, const int* in_sizes, int n_in,
                              void* d_out, int out_size, void* d_ws, size_t ws_size,
                              hipStream_t stream) {
    const float* x    = (const float*)d_in[0];
    const float* W1   = (const float*)d_in[1];
    const float* b1   = (const float*)d_in[2];
    const float* freq = (const float*)d_in[3];
    const float* W2   = (const float*)d_in[4];
    const float* b2   = (const float*)d_in[5];
    float* outp     = (float*)d_out;
    float* freq_out = outp + (size_t)B_ROWS * DOUT;
    unsigned short* w1t = (unsigned short*)d_ws;   // NP*KP bf16 = 186,368 B

    prep_kernel<<<(NP * KP + 255) / 256, 256, 0, stream>>>(W1, freq, w1t, freq_out);
    fused_mlp_kernel<<<B_ROWS / TM, 256, 0, stream>>>(x, w1t, b1, W2, b2, outp, freq_out);
}